// Round 2
// baseline (22.908 us; speedup 1.0000x reference)
//
#include <hip/hip_runtime.h>

#define BATCH 2048
#define UNITS 512
#define DIM   64
#define BG    64      // batch rows per block (= wave width; lane -> row)
#define UC    32      // units per block
#define NU    8       // units per wave
#define OSTR  33      // obuf row stride (conflict-free: bank = (lane+col)%32)

extern "C" __global__ void __launch_bounds__(256, 2)
sausage_v2(const float* __restrict__ x, const float* __restrict__ q1,
           const float* __restrict__ q2, const float* __restrict__ r,
           float* __restrict__ out)
{
  __shared__ double Ld_t[UC];      // t = q1.q12 (fp64)
  __shared__ double Ld_qn[UC];     // ||q12|| (fp64)
  __shared__ float  Ls_w[UC];      // w = q2.q12
  __shared__ float  Ls_n[UC];      // ||q12||^2
  __shared__ float  Ls_q2n[UC];    // ||q2||^2
  __shared__ float  Ls_inv[UC];    // 1/(64 r^2)
  __shared__ float  obuf[BG * OSTR];

  const int tid  = threadIdx.x;
  const int lane = tid & 63;
  const int b0   = blockIdx.x * BG;
  const int u0   = blockIdx.y * UC;

  // ---- issue per-lane x-row loads early (latency hidden under phase A) ----
  const float4* xrow = reinterpret_cast<const float4*>(x + (size_t)(b0 + lane) * DIM);
  float4 xv[16];
  #pragma unroll
  for (int i = 0; i < 16; ++i) xv[i] = xrow[i];

  // ---- phase A: per-u scalars, all 256 threads (u = tid>>3, 8-lane k-slices)
  {
    const int ul = tid >> 3;   // 0..31
    const int sl = tid & 7;    // k-slice of 8
    const float* q1p = q1 + (size_t)(u0 + ul) * DIM + sl * 8;
    const float* q2p = q2 + (size_t)(u0 + ul) * DIM + sl * 8;
    double w = 0.0, nn = 0.0;
    float q2n = 0.0f;
    #pragma unroll
    for (int j = 0; j < 2; ++j) {
      const float4 a = reinterpret_cast<const float4*>(q1p)[j];
      const float4 c = reinterpret_cast<const float4*>(q2p)[j];
      double d;
      d = (double)c.x - (double)a.x; w = fma((double)c.x, d, w); nn = fma(d, d, nn); q2n = fmaf(c.x, c.x, q2n);
      d = (double)c.y - (double)a.y; w = fma((double)c.y, d, w); nn = fma(d, d, nn); q2n = fmaf(c.y, c.y, q2n);
      d = (double)c.z - (double)a.z; w = fma((double)c.z, d, w); nn = fma(d, d, nn); q2n = fmaf(c.z, c.z, q2n);
      d = (double)c.w - (double)a.w; w = fma((double)c.w, d, w); nn = fma(d, d, nn); q2n = fmaf(c.w, c.w, q2n);
    }
    #pragma unroll
    for (int s2 = 1; s2 < 8; s2 <<= 1) {
      w   += __shfl_xor(w, s2, 64);
      nn  += __shfl_xor(nn, s2, 64);
      q2n += __shfl_xor(q2n, s2, 64);
    }
    if (sl == 0) {
      Ld_t[ul]   = w - nn;          // q1.q12 = w - ||q12||^2
      Ld_qn[ul]  = sqrt(nn);
      Ls_w[ul]   = (float)w;
      Ls_n[ul]   = (float)nn;
      Ls_q2n[ul] = q2n;
      const float rv = r[u0 + ul];
      Ls_inv[ul] = 1.0f / (64.0f * rv * rv);
    }
  }

  // ---- unpack x to scalar regs (constant-indexed only) + ||x||^2 ----
  float xr[64];
  #pragma unroll
  for (int i = 0; i < 16; ++i) {
    xr[4*i+0] = xv[i].x; xr[4*i+1] = xv[i].y;
    xr[4*i+2] = xv[i].z; xr[4*i+3] = xv[i].w;
  }
  float xna = 0.0f, xnb = 0.0f, xnc = 0.0f, xnd = 0.0f;
  #pragma unroll
  for (int i = 0; i < 16; ++i) {
    xna = fmaf(xr[4*i+0], xr[4*i+0], xna);
    xnb = fmaf(xr[4*i+1], xr[4*i+1], xnb);
    xnc = fmaf(xr[4*i+2], xr[4*i+2], xnc);
    xnd = fmaf(xr[4*i+3], xr[4*i+3], xnd);
  }
  const float xn = (xna + xnb) + (xnc + xnd);

  __syncthreads();

  // ---- main: per-wave u-slice, q rows are wave-uniform -> scalar loads ----
  const int wsl = __builtin_amdgcn_readfirstlane(tid >> 6);  // wave id 0..3
  for (int uu = 0; uu < NU; ++uu) {
    const int ul = wsl * NU + uu;                // block-local u (uniform)
    const float* q1r = q1 + (size_t)(u0 + ul) * DIM;
    const float* q2r = q2 + (size_t)(u0 + ul) * DIM;

    float d1a = 0.f, d1b = 0.f, d2a = 0.f, d2b = 0.f;
    #pragma unroll
    for (int k = 0; k < 16; ++k) {
      const float4 a = reinterpret_cast<const float4*>(q1r)[k];
      const float4 c = reinterpret_cast<const float4*>(q2r)[k];
      d1a = fmaf(xr[4*k+0], a.x, d1a); d1b = fmaf(xr[4*k+1], a.y, d1b);
      d1a = fmaf(xr[4*k+2], a.z, d1a); d1b = fmaf(xr[4*k+3], a.w, d1b);
      d2a = fmaf(xr[4*k+0], c.x, d2a); d2b = fmaf(xr[4*k+1], c.y, d2b);
      d2a = fmaf(xr[4*k+2], c.z, d2a); d2b = fmaf(xr[4*k+3], c.w, d2b);
    }
    const float d1 = d1a + d1b;
    const float d2 = d2a + d2b;

    float af = d2 - d1;                       // a = x.q12
    const double t  = Ld_t[ul];
    const double qn = Ld_qn[ul];
    double s64 = (double)af - t;

    // rare fp64 fixup when any lane is near a branch boundary
    const bool nearb = (fabs(s64) < 1e-4) || (fabs(s64 - qn) < 1e-4);
    if (__any(nearb)) {
      double a64 = 0.0;
      #pragma unroll
      for (int k = 0; k < 16; ++k) {
        const float4 a4 = reinterpret_cast<const float4*>(q1r)[k];
        const float4 c4 = reinterpret_cast<const float4*>(q2r)[k];
        a64 = fma((double)xr[4*k+0], (double)c4.x - (double)a4.x, a64);
        a64 = fma((double)xr[4*k+1], (double)c4.y - (double)a4.y, a64);
        a64 = fma((double)xr[4*k+2], (double)c4.z - (double)a4.z, a64);
        a64 = fma((double)xr[4*k+3], (double)c4.w - (double)a4.w, a64);
      }
      s64 = a64 - t;
      af  = (float)a64;
    }

    float l;
    if (s64 < 0.0)      l = 1.0f;
    else if (s64 < qn)  l = (float)s64;       // k_norm = |s| = s in this branch
    else                l = 0.0f;

    const float dsq = fmaf(-2.0f, d2, xn) + Ls_q2n[ul]
                    + 2.0f * l * (af - Ls_w[ul]) + l * l * Ls_n[ul];
    obuf[lane * OSTR + ul] = __expf(-dsq * Ls_inv[ul]);
  }

  __syncthreads();

  // ---- coalesced store: thread -> (row rr, 8-col segment) ----
  {
    const int rr = tid >> 2;          // 0..63
    const int c0 = (tid & 3) * 8;     // 0,8,16,24
    float4 v0, v1;
    v0.x = obuf[rr * OSTR + c0 + 0]; v0.y = obuf[rr * OSTR + c0 + 1];
    v0.z = obuf[rr * OSTR + c0 + 2]; v0.w = obuf[rr * OSTR + c0 + 3];
    v1.x = obuf[rr * OSTR + c0 + 4]; v1.y = obuf[rr * OSTR + c0 + 5];
    v1.z = obuf[rr * OSTR + c0 + 6]; v1.w = obuf[rr * OSTR + c0 + 7];
    float4* op = reinterpret_cast<float4*>(out + (size_t)(b0 + rr) * UNITS + u0 + c0);
    op[0] = v0;
    op[1] = v1;
  }
}

extern "C" void kernel_launch(void* const* d_in, const int* in_sizes, int n_in,
                              void* d_out, int out_size, void* d_ws, size_t ws_size,
                              hipStream_t stream) {
  const float* x  = (const float*)d_in[0];
  const float* q1 = (const float*)d_in[1];
  const float* q2 = (const float*)d_in[2];
  const float* r  = (const float*)d_in[3];
  float* out = (float*)d_out;
  dim3 grid(BATCH / BG, UNITS / UC);   // (32, 16) = 512 blocks, 2 per CU
  sausage_v2<<<grid, 256, 0, stream>>>(x, q1, q2, r, out);
}

// Round 3
// 12.799 us; speedup vs baseline: 1.7899x; 1.7899x over previous
//
#include <hip/hip_runtime.h>

#define BATCH 2048
#define UNITS 512
#define DIM   64
#define TB    64      // batch rows per block
#define TU    32      // units per block
#define XS    68      // x-tile k-row stride (words): bank = (4k+b)%32, 16B-aligned rows
#define QS    36      // q-tile k-row stride (words)

extern "C" __global__ void __launch_bounds__(256, 2)
sausage_v3(const float* __restrict__ x, const float* __restrict__ q1,
           const float* __restrict__ q2, const float* __restrict__ r,
           float* __restrict__ out)
{
  __shared__ float sx [64 * XS];                 // x^T  [k][b]
  __shared__ float sq1[64 * QS];                 // q1^T [k][u]
  __shared__ float sq2[64 * QS];                 // q2^T [k][u]
  __shared__ float Lt[TU], Lqn[TU], Lw[TU], Lnn[TU], Lq2n[TU], Linv[TU];
  __shared__ float Lxn[TB];

  const int tid  = threadIdx.x;
  const int lane = tid & 63;
  const int wid  = tid >> 6;
  const int b0   = blockIdx.x * TB;
  const int u0   = blockIdx.y * TU;

  // early r load: latency hidden under staging; tid<32 == the phase-A writers
  float rv = 1.0f;
  if (tid < TU) rv = r[u0 + tid];

  // ================= staging: global (row-major) -> LDS (k-major) ============
  {
    const int rg = tid >> 4;       // 0..15 : 4-row group
    const int ks = tid & 15;       // 0..15 : 4-col k segment (fast -> coalesced)
    const float4 v0 = *(const float4*)(x + (size_t)(b0 + 4*rg + 0) * DIM + 4*ks);
    const float4 v1 = *(const float4*)(x + (size_t)(b0 + 4*rg + 1) * DIM + 4*ks);
    const float4 v2 = *(const float4*)(x + (size_t)(b0 + 4*rg + 2) * DIM + 4*ks);
    const float4 v3 = *(const float4*)(x + (size_t)(b0 + 4*rg + 3) * DIM + 4*ks);
    *(float4*)(sx + (4*ks+0)*XS + 4*rg) = make_float4(v0.x, v1.x, v2.x, v3.x);
    *(float4*)(sx + (4*ks+1)*XS + 4*rg) = make_float4(v0.y, v1.y, v2.y, v3.y);
    *(float4*)(sx + (4*ks+2)*XS + 4*rg) = make_float4(v0.z, v1.z, v2.z, v3.z);
    *(float4*)(sx + (4*ks+3)*XS + 4*rg) = make_float4(v0.w, v1.w, v2.w, v3.w);

    const float* qsrc = (tid & 128) ? q2 : q1;   // waves 0-1: q1, waves 2-3: q2
    float*       qdst = (tid & 128) ? sq2 : sq1;
    const int ug8 = (tid >> 4) & 7;              // 0..7 : 4-unit group
    const float4 w0 = *(const float4*)(qsrc + (size_t)(u0 + 4*ug8 + 0) * DIM + 4*ks);
    const float4 w1 = *(const float4*)(qsrc + (size_t)(u0 + 4*ug8 + 1) * DIM + 4*ks);
    const float4 w2 = *(const float4*)(qsrc + (size_t)(u0 + 4*ug8 + 2) * DIM + 4*ks);
    const float4 w3 = *(const float4*)(qsrc + (size_t)(u0 + 4*ug8 + 3) * DIM + 4*ks);
    *(float4*)(qdst + (4*ks+0)*QS + 4*ug8) = make_float4(w0.x, w1.x, w2.x, w3.x);
    *(float4*)(qdst + (4*ks+1)*QS + 4*ug8) = make_float4(w0.y, w1.y, w2.y, w3.y);
    *(float4*)(qdst + (4*ks+2)*QS + 4*ug8) = make_float4(w0.z, w1.z, w2.z, w3.z);
    *(float4*)(qdst + (4*ks+3)*QS + 4*ug8) = make_float4(w0.w, w1.w, w2.w, w3.w);
  }
  __syncthreads();

  // ================= phase A: per-u scalars (wave 0) + per-b ||x||^2 (wave 1) =
  if (wid == 0) {
    const int u = lane & 31;
    const int h = lane >> 5;            // k-half
    float w = 0.0f, nn = 0.0f, q2n = 0.0f;
    #pragma unroll
    for (int m = 0; m < 32; ++m) {
      const int k = 32*h + m;
      const float a = sq1[k*QS + u];
      const float c = sq2[k*QS + u];
      const float d = c - a;                       // q12
      w   = fmaf(c, d, w);
      nn  = fmaf(d, d, nn);
      q2n = fmaf(c, c, q2n);
    }
    w   += __shfl_xor(w, 32);
    nn  += __shfl_xor(nn, 32);
    q2n += __shfl_xor(q2n, 32);
    if (h == 0) {
      Lt[u]   = w - nn;                 // t = q1.q12
      Lqn[u]  = sqrtf(nn);              // ||q12||
      Lw[u]   = w;                      // q2.q12
      Lnn[u]  = nn;                     // ||q12||^2
      Lq2n[u] = q2n;                    // ||q2||^2
      Linv[u] = 1.0f / (64.0f * rv * rv);
    }
  } else if (wid == 1) {
    const int b = lane;
    float s0 = 0.f, s1 = 0.f, s2 = 0.f, s3 = 0.f;
    #pragma unroll
    for (int k = 0; k < 64; k += 4) {
      const float a0 = sx[(k+0)*XS + b];
      const float a1 = sx[(k+1)*XS + b];
      const float a2 = sx[(k+2)*XS + b];
      const float a3 = sx[(k+3)*XS + b];
      s0 = fmaf(a0, a0, s0); s1 = fmaf(a1, a1, s1);
      s2 = fmaf(a2, a2, s2); s3 = fmaf(a3, a3, s3);
    }
    Lxn[b] = (s0 + s1) + (s2 + s3);
  }
  __syncthreads();

  // ================= main: micro-tile 4b x 2u, imm-offset ds_reads ===========
  const int ug = tid & 15;              // unit granule (fast -> coalesced stores)
  const int bg = tid >> 4;              // batch granule
  const float* px = sx  + 4*bg;
  const float* p1 = sq1 + 2*ug;
  const float* p2 = sq2 + 2*ug;

  float d1[4][2] = {{0.f,0.f},{0.f,0.f},{0.f,0.f},{0.f,0.f}};
  float d2[4][2] = {{0.f,0.f},{0.f,0.f},{0.f,0.f},{0.f,0.f}};

  #pragma unroll
  for (int k = 0; k < 64; ++k) {
    const float4 xv = *(const float4*)(px + k*XS);
    const float2 av = *(const float2*)(p1 + k*QS);
    const float2 cv = *(const float2*)(p2 + k*QS);
    const float xs0 = xv.x, xs1 = xv.y, xs2 = xv.z, xs3 = xv.w;
    d1[0][0] = fmaf(xs0, av.x, d1[0][0]);  d1[0][1] = fmaf(xs0, av.y, d1[0][1]);
    d1[1][0] = fmaf(xs1, av.x, d1[1][0]);  d1[1][1] = fmaf(xs1, av.y, d1[1][1]);
    d1[2][0] = fmaf(xs2, av.x, d1[2][0]);  d1[2][1] = fmaf(xs2, av.y, d1[2][1]);
    d1[3][0] = fmaf(xs3, av.x, d1[3][0]);  d1[3][1] = fmaf(xs3, av.y, d1[3][1]);
    d2[0][0] = fmaf(xs0, cv.x, d2[0][0]);  d2[0][1] = fmaf(xs0, cv.y, d2[0][1]);
    d2[1][0] = fmaf(xs1, cv.x, d2[1][0]);  d2[1][1] = fmaf(xs1, cv.y, d2[1][1]);
    d2[2][0] = fmaf(xs2, cv.x, d2[2][0]);  d2[2][1] = fmaf(xs2, cv.y, d2[2][1]);
    d2[3][0] = fmaf(xs3, cv.x, d2[3][0]);  d2[3][1] = fmaf(xs3, cv.y, d2[3][1]);
  }

  // ================= epilogue + coalesced float2 stores ======================
  float tt[2], qn[2], ww[2], nn2[2], qq[2], iv[2];
  #pragma unroll
  for (int jj = 0; jj < 2; ++jj) {
    const int ul = 2*ug + jj;
    tt[jj] = Lt[ul];  qn[jj] = Lqn[ul];  ww[jj] = Lw[ul];
    nn2[jj] = Lnn[ul]; qq[jj] = Lq2n[ul]; iv[jj] = Linv[ul];
  }
  #pragma unroll
  for (int i = 0; i < 4; ++i) {
    const float xnv = Lxn[4*bg + i];
    float2 o;
    #pragma unroll
    for (int jj = 0; jj < 2; ++jj) {
      const float a = d2[i][jj] - d1[i][jj];     // x.q12
      const float s = a - tt[jj];                // (x-q1).q12
      const float l = (s < 0.0f) ? 1.0f : ((s < qn[jj]) ? s : 0.0f);
      const float dsq = fmaf(-2.0f, d2[i][jj], xnv) + qq[jj]
                      + 2.0f * l * (a - ww[jj]) + l * l * nn2[jj];
      (jj ? o.y : o.x) = __expf(-dsq * iv[jj]);
    }
    *(float2*)(out + (size_t)(b0 + 4*bg + i) * UNITS + u0 + 2*ug) = o;
  }
}

extern "C" void kernel_launch(void* const* d_in, const int* in_sizes, int n_in,
                              void* d_out, int out_size, void* d_ws, size_t ws_size,
                              hipStream_t stream) {
  const float* x  = (const float*)d_in[0];
  const float* q1 = (const float*)d_in[1];
  const float* q2 = (const float*)d_in[2];
  const float* r  = (const float*)d_in[3];
  float* out = (float*)d_out;
  dim3 grid(BATCH / TB, UNITS / TU);   // (32, 16) = 512 blocks = 2 per CU
  sausage_v3<<<grid, 256, 0, stream>>>(x, q1, q2, r, out);
}

// Round 4
// 11.507 us; speedup vs baseline: 1.9907x; 1.1122x over previous
//
#include <hip/hip_runtime.h>

#define BATCH 2048
#define UNITS 512
#define DIM   64
#define TB    64      // batch rows per block
#define TU    32      // units per block

typedef __attribute__((ext_vector_type(8))) short short8v;   // 8 bf16 (4 VGPR)
typedef __attribute__((ext_vector_type(4))) float float4v;   // MFMA C/D

// f32 -> bf16 round-to-nearest-even (finite inputs)
__device__ __forceinline__ unsigned short f2bf(float f) {
  union { float f; unsigned u; } v; v.f = f;
  return (unsigned short)((v.u + 0x7FFFu + ((v.u >> 16) & 1u)) >> 16);
}

// 16B-granule XOR swizzle in ushort units: flips bits 3..5 of k-index by row&7
__device__ __forceinline__ int swz(int row, int k) {
  return (row * 64 + k) ^ ((row & 7) << 3);
}

extern "C" __global__ void __launch_bounds__(256, 2)
sausage_v4(const float* __restrict__ x, const float* __restrict__ q1,
           const float* __restrict__ q2, const float* __restrict__ r,
           float* __restrict__ out)
{
  __shared__ __align__(16) unsigned short sX [TB * 64];   // 8 KB bf16 x-tile
  __shared__ __align__(16) unsigned short sQ1[TU * 64];   // 4 KB bf16 q1-tile
  __shared__ __align__(16) unsigned short sQ2[TU * 64];   // 4 KB bf16 q2-tile
  __shared__ float Lt[TU], Lqn[TU], Lw[TU], Lnn[TU], Lq2n[TU], Linv[TU];
  __shared__ float Lxn[TB];

  const int tid = threadIdx.x;
  const int b0  = blockIdx.x * TB;
  const int u0  = blockIdx.y * TU;

  // ============ staging + fused scalar reductions (one pass, fp32) ===========
  if (tid < 128) {
    // threads 0-127: q1 & q2 -> bf16 LDS; per-u scalars via 4-lane reduce
    const int u   = tid >> 2;          // 0..31
    const int seg = tid & 3;           // 16-k segment
    const float* q1p = q1 + (size_t)(u0 + u) * DIM + seg * 16;
    const float* q2p = q2 + (size_t)(u0 + u) * DIM + seg * 16;
    float av[16], cv[16];
    #pragma unroll
    for (int j = 0; j < 4; ++j) {
      const float4 a4 = reinterpret_cast<const float4*>(q1p)[j];
      const float4 c4 = reinterpret_cast<const float4*>(q2p)[j];
      av[4*j+0] = a4.x; av[4*j+1] = a4.y; av[4*j+2] = a4.z; av[4*j+3] = a4.w;
      cv[4*j+0] = c4.x; cv[4*j+1] = c4.y; cv[4*j+2] = c4.z; cv[4*j+3] = c4.w;
    }
    float nn = 0.f, w = 0.f, q2n = 0.f;
    #pragma unroll
    for (int j = 0; j < 16; ++j) {
      const float d = cv[j] - av[j];
      nn  = fmaf(d, d, nn);
      w   = fmaf(cv[j], d, w);
      q2n = fmaf(cv[j], cv[j], q2n);
    }
    #pragma unroll
    for (int h = 0; h < 2; ++h) {
      union { unsigned short u16[8]; short8v v; } p1, p2;
      #pragma unroll
      for (int j = 0; j < 8; ++j) {
        p1.u16[j] = f2bf(av[8*h+j]);
        p2.u16[j] = f2bf(cv[8*h+j]);
      }
      const int idx = swz(u, seg * 16 + 8 * h);
      *reinterpret_cast<short8v*>(&sQ1[idx]) = p1.v;
      *reinterpret_cast<short8v*>(&sQ2[idx]) = p2.v;
    }
    nn  += __shfl_xor(nn, 1);  nn  += __shfl_xor(nn, 2);
    w   += __shfl_xor(w, 1);   w   += __shfl_xor(w, 2);
    q2n += __shfl_xor(q2n, 1); q2n += __shfl_xor(q2n, 2);
    if (seg == 0) {
      const float rv = r[u0 + u];
      Lt[u]   = w - nn;            // q1.q12
      Lqn[u]  = sqrtf(nn);         // ||q12||
      Lw[u]   = w;                 // q2.q12
      Lnn[u]  = nn;                // ||q12||^2
      Lq2n[u] = q2n;               // ||q2||^2
      Linv[u] = 1.0f / (64.0f * rv * rv);
    }
  } else {
    // threads 128-255: x -> bf16 LDS; per-b ||x||^2 via 2-lane reduce
    const int tt   = tid - 128;
    const int row  = tt >> 1;          // 0..63
    const int half = tt & 1;           // 32-k half
    const float* xp = x + (size_t)(b0 + row) * DIM + half * 32;
    float v[32];
    #pragma unroll
    for (int j = 0; j < 8; ++j) {
      const float4 v4 = reinterpret_cast<const float4*>(xp)[j];
      v[4*j+0] = v4.x; v[4*j+1] = v4.y; v[4*j+2] = v4.z; v[4*j+3] = v4.w;
    }
    float xn = 0.f;
    #pragma unroll
    for (int j = 0; j < 32; ++j) xn = fmaf(v[j], v[j], xn);
    #pragma unroll
    for (int h = 0; h < 4; ++h) {
      union { unsigned short u16[8]; short8v v; } p;
      #pragma unroll
      for (int j = 0; j < 8; ++j) p.u16[j] = f2bf(v[8*h+j]);
      const int idx = swz(row, half * 32 + 8 * h);
      *reinterpret_cast<short8v*>(&sX[idx]) = p.v;
    }
    xn += __shfl_xor(xn, 1);
    if (half == 0) Lxn[row] = xn;
  }
  __syncthreads();

  // ============ main: 8 ds_read_b128 + 8 MFMA per wave =======================
  const int lane = tid & 63;
  const int wid  = tid >> 6;
  const int wr   = wid >> 1;            // 0,1 : 32-row half
  const int wc   = wid & 1;             // 0,1 : 16-unit half
  const int l15  = lane & 15;
  const int lk   = lane >> 4;
  const int kb   = lk * 8;

  short8v a_frag[2][2], b1_frag[2], b2_frag[2];
  const int urow = wc * 16 + l15;
  #pragma unroll
  for (int ks = 0; ks < 2; ++ks) {
    const int qi = swz(urow, ks * 32 + kb);
    b1_frag[ks] = *reinterpret_cast<const short8v*>(&sQ1[qi]);
    b2_frag[ks] = *reinterpret_cast<const short8v*>(&sQ2[qi]);
    #pragma unroll
    for (int mt = 0; mt < 2; ++mt) {
      const int mrow = wr * 32 + mt * 16 + l15;
      a_frag[mt][ks] = *reinterpret_cast<const short8v*>(&sX[swz(mrow, ks * 32 + kb)]);
    }
  }

  float4v acc1[2], acc2[2];
  #pragma unroll
  for (int mt = 0; mt < 2; ++mt) {
    acc1[mt] = (float4v){0.f, 0.f, 0.f, 0.f};
    acc2[mt] = (float4v){0.f, 0.f, 0.f, 0.f};
  }
  #pragma unroll
  for (int mt = 0; mt < 2; ++mt)
    #pragma unroll
    for (int ks = 0; ks < 2; ++ks) {
      acc1[mt] = __builtin_amdgcn_mfma_f32_16x16x32_bf16(a_frag[mt][ks], b1_frag[ks], acc1[mt], 0, 0, 0);
      acc2[mt] = __builtin_amdgcn_mfma_f32_16x16x32_bf16(a_frag[mt][ks], b2_frag[ks], acc2[mt], 0, 0, 0);
    }

  // ============ epilogue: branchless l-select + exp, direct stores ===========
  const float t_   = Lt[urow];
  const float qn_  = Lqn[urow];
  const float w_   = Lw[urow];
  const float nn_  = Lnn[urow];
  const float q2n_ = Lq2n[urow];
  const float inv_ = Linv[urow];

  #pragma unroll
  for (int mt = 0; mt < 2; ++mt) {
    const int rbase = wr * 32 + mt * 16 + lk * 4;   // C/D: row=(lane>>4)*4+reg
    #pragma unroll
    for (int j = 0; j < 4; ++j) {
      const float d1 = acc1[mt][j];
      const float d2 = acc2[mt][j];
      const float a  = d2 - d1;                     // x.q12
      const float s  = a - t_;                      // (x-q1).q12
      const float l  = (s < 0.0f) ? 1.0f : ((s < qn_) ? s : 0.0f);
      const float dsq = fmaf(-2.0f, d2, Lxn[rbase + j]) + q2n_
                      + 2.0f * l * (a - w_) + l * l * nn_;
      out[(size_t)(b0 + rbase + j) * UNITS + u0 + urow] = __expf(-dsq * inv_);
    }
  }
}

extern "C" void kernel_launch(void* const* d_in, const int* in_sizes, int n_in,
                              void* d_out, int out_size, void* d_ws, size_t ws_size,
                              hipStream_t stream) {
  const float* x  = (const float*)d_in[0];
  const float* q1 = (const float*)d_in[1];
  const float* q2 = (const float*)d_in[2];
  const float* r  = (const float*)d_in[3];
  float* out = (float*)d_out;
  (void)d_ws; (void)ws_size;
  dim3 grid(BATCH / TB, UNITS / TU);   // (32, 16) = 512 blocks = 2 per CU
  sausage_v4<<<grid, 256, 0, stream>>>(x, q1, q2, r, out);
}

// Round 5
// 11.079 us; speedup vs baseline: 2.0678x; 1.0387x over previous
//
#include <hip/hip_runtime.h>

#define BATCH 2048
#define UNITS 512
#define DIM   64

typedef __attribute__((ext_vector_type(8))) short short8v;   // 8 bf16 (4 VGPR)
typedef __attribute__((ext_vector_type(4))) float float4v;   // MFMA C/D

// f32 -> bf16 round-to-nearest-even (finite inputs)
__device__ __forceinline__ unsigned short f2bf(float f) {
  union { float f; unsigned u; } v; v.f = f;
  return (unsigned short)((v.u + 0x7FFFu + ((v.u >> 16) & 1u)) >> 16);
}

__device__ __forceinline__ short8v pack8(const float* s) {
  union { unsigned short u16[8]; short8v v; } p;
  #pragma unroll
  for (int j = 0; j < 8; ++j) p.u16[j] = f2bf(s[j]);
  return p.v;
}

extern "C" __global__ void __launch_bounds__(64, 2)
sausage_v5(const float* __restrict__ x, const float* __restrict__ q1,
           const float* __restrict__ q2, const float* __restrict__ r,
           float* __restrict__ out)
{
  const int lane = threadIdx.x;        // 0..63
  const int l15  = lane & 15;          // MFMA row/col within 16
  const int lk   = lane >> 4;          // k-group 0..3
  const int b0   = blockIdx.x * 32;
  const int u0   = blockIdx.y * 16;

  // ---------------- all global loads issued up front (L2-resident) ----------
  float q1f[16], q2f[16], xf[2][16];
  {
    const float* q1r = q1 + (size_t)(u0 + l15) * DIM + lk * 8;
    const float* q2r = q2 + (size_t)(u0 + l15) * DIM + lk * 8;
    #pragma unroll
    for (int ks = 0; ks < 2; ++ks) {
      *(float4*)&q1f[8*ks + 0] = *(const float4*)(q1r + ks * 32);
      *(float4*)&q1f[8*ks + 4] = *(const float4*)(q1r + ks * 32 + 4);
      *(float4*)&q2f[8*ks + 0] = *(const float4*)(q2r + ks * 32);
      *(float4*)&q2f[8*ks + 4] = *(const float4*)(q2r + ks * 32 + 4);
    }
    #pragma unroll
    for (int mt = 0; mt < 2; ++mt) {
      const float* xr = x + (size_t)(b0 + mt * 16 + l15) * DIM + lk * 8;
      #pragma unroll
      for (int ks = 0; ks < 2; ++ks) {
        *(float4*)&xf[mt][8*ks + 0] = *(const float4*)(xr + ks * 32);
        *(float4*)&xf[mt][8*ks + 4] = *(const float4*)(xr + ks * 32 + 4);
      }
    }
  }
  const float rv = r[u0 + l15];

  // ---------------- per-u scalars from this lane's fp32 k-slice -------------
  // lane's 16 k-values across lk-groups tile k=0..63 exactly
  float nn = 0.f, w = 0.f, q2n = 0.f;
  #pragma unroll
  for (int j = 0; j < 16; ++j) {
    const float d = q2f[j] - q1f[j];
    nn  = fmaf(d, d, nn);
    w   = fmaf(q2f[j], d, w);
    q2n = fmaf(q2f[j], q2f[j], q2n);
  }
  float xnp0 = 0.f, xnp1 = 0.f;
  #pragma unroll
  for (int j = 0; j < 16; ++j) {
    xnp0 = fmaf(xf[0][j], xf[0][j], xnp0);
    xnp1 = fmaf(xf[1][j], xf[1][j], xnp1);
  }
  // reduce across the 4 lk-groups (lanes sharing l15): xor 16, then xor 32
  nn   += __shfl_xor(nn, 16);   nn   += __shfl_xor(nn, 32);
  w    += __shfl_xor(w, 16);    w    += __shfl_xor(w, 32);
  q2n  += __shfl_xor(q2n, 16);  q2n  += __shfl_xor(q2n, 32);
  xnp0 += __shfl_xor(xnp0, 16); xnp0 += __shfl_xor(xnp0, 32);
  xnp1 += __shfl_xor(xnp1, 16); xnp1 += __shfl_xor(xnp1, 32);

  const float t_   = w - nn;             // q1.q12
  const float qn_  = sqrtf(nn);          // ||q12||
  const float inv_ = 1.0f / (64.0f * rv * rv);

  // ---------------- convert to bf16 fragments, 8 MFMAs ----------------------
  short8v b1_frag[2], b2_frag[2], a_frag[2][2];
  #pragma unroll
  for (int ks = 0; ks < 2; ++ks) {
    b1_frag[ks] = pack8(&q1f[8 * ks]);
    b2_frag[ks] = pack8(&q2f[8 * ks]);
    a_frag[0][ks] = pack8(&xf[0][8 * ks]);
    a_frag[1][ks] = pack8(&xf[1][8 * ks]);
  }
  float4v acc1[2], acc2[2];
  #pragma unroll
  for (int mt = 0; mt < 2; ++mt) {
    acc1[mt] = (float4v){0.f, 0.f, 0.f, 0.f};
    acc2[mt] = (float4v){0.f, 0.f, 0.f, 0.f};
    #pragma unroll
    for (int ks = 0; ks < 2; ++ks) {
      acc1[mt] = __builtin_amdgcn_mfma_f32_16x16x32_bf16(a_frag[mt][ks], b1_frag[ks], acc1[mt], 0, 0, 0);
      acc2[mt] = __builtin_amdgcn_mfma_f32_16x16x32_bf16(a_frag[mt][ks], b2_frag[ks], acc2[mt], 0, 0, 0);
    }
  }

  // ---------------- redistribute ||x||^2 to C/D row owners ------------------
  // xnp{mt} (post-reduce) holds row mt*16+l15; epilogue lane needs rows lk*4+j
  float xnv[2][4];
  #pragma unroll
  for (int j = 0; j < 4; ++j) {
    xnv[0][j] = __shfl(xnp0, lk * 4 + j);
    xnv[1][j] = __shfl(xnp1, lk * 4 + j);
  }

  // ---------------- epilogue: l-select + exp + direct stores ----------------
  #pragma unroll
  for (int mt = 0; mt < 2; ++mt) {
    #pragma unroll
    for (int j = 0; j < 4; ++j) {
      const float d1 = acc1[mt][j];
      const float d2 = acc2[mt][j];
      const float a  = d2 - d1;                 // x.q12
      const float s  = a - t_;                  // (x-q1).q12
      const float l  = (s < 0.0f) ? 1.0f : ((s < qn_) ? s : 0.0f);
      const float dsq = fmaf(-2.0f, d2, xnv[mt][j]) + q2n
                      + 2.0f * l * (a - w) + l * l * nn;
      const int row = b0 + mt * 16 + lk * 4 + j;   // C/D: row=(lane>>4)*4+reg
      out[(size_t)row * UNITS + u0 + l15] = __expf(-dsq * inv_);
    }
  }
}

extern "C" void kernel_launch(void* const* d_in, const int* in_sizes, int n_in,
                              void* d_out, int out_size, void* d_ws, size_t ws_size,
                              hipStream_t stream) {
  const float* x  = (const float*)d_in[0];
  const float* q1 = (const float*)d_in[1];
  const float* q2 = (const float*)d_in[2];
  const float* r  = (const float*)d_in[3];
  float* out = (float*)d_out;
  (void)d_ws; (void)ws_size;
  dim3 grid(BATCH / 32, UNITS / 16);   // (64, 32) = 2048 single-wave blocks
  sausage_v5<<<grid, 64, 0, stream>>>(x, q1, q2, r, out);
}